// Round 6
// baseline (48276.855 us; speedup 1.0000x reference)
//
#include <hip/hip_runtime.h>
#include <hip/hip_bf16.h>
#include <math.h>

#define Dm 768
#define Hn 12
#define DEPTH 12
#define NPATCH 196
#define Ntok 197
#define MLPD 3072
#define NC 1000
#define Bb 32
#define BC 8            /* attention batch-chunk */
#define HD 64
#define SCALE 0.125f
#define TOKENS (Bb*Ntok)      /* 6304 */
#define NN (Ntok*Ntok)        /* 38809 */

typedef __hip_bfloat16 bf16;

__device__ __forceinline__ float b2f(bf16 x){ return __bfloat162float(x); }
__device__ __forceinline__ float ldf(const float* p){ return *p; }
__device__ __forceinline__ float ldf(const bf16*  p){ return __bfloat162float(*p); }
__device__ __forceinline__ void  stf(float* p, float v){ *p = v; }
__device__ __forceinline__ void  stf(bf16*  p, float v){ *p = __float2bfloat16(v); }

// Runtime-dtype input accessor: f==1 -> bf16, f==0 -> fp32.
__device__ __forceinline__ float ldin(const void* p, long i, int f){
  return f ? __bfloat162float(((const bf16*)p)[i]) : ((const float*)p)[i];
}

struct P23 { const void* p[23]; };

// ---- per-input dtype detection (fp32 low-half mantissas look like wild bf16
// exponents; fp32 ones-arrays show zeros exactly on even lanes) --------------
__global__ void detect_k(P23 ptrs, int* __restrict__ flags){
  int b = blockIdx.x;
  const unsigned short* u = (const unsigned short*)ptrs.p[b];
  int lane = threadIdx.x;
  unsigned short v = u[lane];
  int ex = (v >> 7) & 0xFF;
  bool bad = (ex > 140) || (ex != 0 && ex < 90);
  bool isz = (v == 0);
  unsigned long long bb = __ballot(bad);
  unsigned long long zb = __ballot(isz);
  if (lane == 0)
    flags[b] = (bb != 0ULL || zb == 0x5555555555555555ULL) ? 0 : 1;
}

// ---- patch extraction: x[B,3,224,224] -> xp[B*196, 768] fp32 ----------------
__global__ void patch_extract(const void* __restrict__ x, const int* __restrict__ F,
                              float* __restrict__ xp){
  int fx = F[0];
  int idx = blockIdx.x*256 + threadIdx.x;
  if (idx >= Bb*NPATCH*Dm) return;
  int k = idx % Dm;
  int t = idx / Dm;
  int p = t % NPATCH; int b = t / NPATCH;
  int c  = k >> 8;
  int r  = (k >> 4) & 15;
  int cc = k & 15;
  int pi = p / 14, pj = p % 14;
  long src = ((long)(b*3 + c)*224 + pi*16 + r)*224 + pj*16 + cc;
  xp[idx] = ldin(x, src, fx);
}

// ---- generic GEMM: C[M,N] = (A[M,K] @ W[N,K]^T) + bias ----------------------
template<int ACT, bool ACCUM, typename TA, typename TC>
__global__ void gemm_bt(const TA* __restrict__ A, int lda,
                        const void* __restrict__ W, long woff, int ldw,
                        const void* __restrict__ bias, long boff,
                        const int* __restrict__ F, int wi, int bi,
                        TC* __restrict__ C, int ldc,
                        int M, int Ncols, int K)
{
  int fw = F[wi];
  int fb = (bi >= 0) ? F[bi] : 0;
  __shared__ float As[32][33];
  __shared__ float Ws[32][33];
  int tid = threadIdx.x;
  int rowBase = blockIdx.y*32;
  int colBase = blockIdx.x*32;
  int tx = tid & 15, ty = tid >> 4;
  float acc[2][2] = {};
  for (int k0 = 0; k0 < K; k0 += 32){
    #pragma unroll
    for (int i = 0; i < 4; i++){
      int e = tid + i*256;
      int r = e >> 5, c = e & 31;
      int gr = rowBase + r, gc = k0 + c;
      As[r][c] = (gr < M) ? ldf(&A[(long)gr*lda + gc]) : 0.f;
      int wr = colBase + r;
      Ws[r][c] = (wr < Ncols) ? ldin(W, woff + (long)wr*ldw + gc, fw) : 0.f;
    }
    __syncthreads();
    #pragma unroll
    for (int kk = 0; kk < 32; kk++){
      float a0 = As[ty][kk], a1 = As[ty+16][kk];
      float b0 = Ws[tx][kk], b1 = Ws[tx+16][kk];
      acc[0][0] += a0*b0; acc[0][1] += a0*b1;
      acc[1][0] += a1*b0; acc[1][1] += a1*b1;
    }
    __syncthreads();
  }
  #pragma unroll
  for (int i=0;i<2;i++)
  #pragma unroll
  for (int j=0;j<2;j++){
    int r = rowBase + ty + i*16, c = colBase + tx + j*16;
    if (r < M && c < Ncols){
      float v = acc[i][j];
      if (bi >= 0) v += ldin(bias, boff + c, fb);
      if (ACT==1) v = 0.5f*v*(1.f + erff(v*0.70710678118f));
      if (ACCUM){ float* cp = (float*)&C[(long)r*ldc+c]; *cp += v; }
      else stf(&C[(long)r*ldc+c], v);
    }
  }
}

// ---- assemble residual stream T from patch-embed + cls + pos ----------------
__global__ void assemble_t(const float* __restrict__ pe,
                           const void* __restrict__ bpe, const void* __restrict__ cls,
                           const void* __restrict__ pos, const int* __restrict__ F,
                           float* __restrict__ T)
{
  int f2 = F[2], f3 = F[3], f4 = F[4];
  int idx = blockIdx.x*256 + threadIdx.x;
  if (idx >= TOKENS*Dm) return;
  int d = idx % Dm;
  int t = idx / Dm;
  int n = t % Ntok, b = t / Ntok;
  float v;
  if (n == 0) v = ldin(cls, d, f3);
  else        v = pe[((long)b*NPATCH + n-1)*Dm + d] + ldin(bpe, d, f2);
  T[idx] = v + ldin(pos, (long)n*Dm + d, f4);
}

// ---- layernorm: one block per row, D=768 ------------------------------------
__global__ void layernorm(const float* __restrict__ X, long xstride,
                          const void* __restrict__ g, long goff, int gi,
                          const void* __restrict__ b, long boff, int bi,
                          const int* __restrict__ F,
                          float* __restrict__ Y, long ystride)
{
  int fg = F[gi], fb = F[bi];
  int row = blockIdx.x;
  const float* xr = X + (long)row*xstride;
  float* yr = Y + (long)row*ystride;
  int tid = threadIdx.x;
  float x0 = xr[tid], x1 = xr[tid+256], x2 = xr[tid+512];
  float s  = x0+x1+x2;
  float sq = x0*x0 + x1*x1 + x2*x2;
  __shared__ float red[6][2];
  for (int off=32; off; off>>=1){ s += __shfl_down(s, off); sq += __shfl_down(sq, off); }
  int wave = tid >> 6, lane = tid & 63;
  if (lane==0){ red[wave][0]=s; red[wave][1]=sq; }
  __syncthreads();
  if (tid==0){
    float S=0, SQ=0;
    for (int w=0;w<4;w++){ S+=red[w][0]; SQ+=red[w][1]; }
    red[4][0] = S*(1.f/768.f);
    red[4][1] = SQ*(1.f/768.f);
  }
  __syncthreads();
  float m  = red[4][0];
  float var= red[4][1] - m*m;
  float rs = rsqrtf(var + 1e-6f);
  yr[tid]     = (x0-m)*rs*ldin(g,goff+tid,fg)     + ldin(b,boff+tid,fb);
  yr[tid+256] = (x1-m)*rs*ldin(g,goff+tid+256,fg) + ldin(b,boff+tid+256,fb);
  yr[tid+512] = (x2-m)*rs*ldin(g,goff+tid+512,fg) + ldin(b,boff+tid+512,fb);
}

// ---- attention scores (batch-chunk): a[bl,h,n,m] = SCALE*q.k ----------------
__global__ void attn_scores(const bf16* __restrict__ QKV, bf16* __restrict__ A1,
                            int bbase){
  int z = blockIdx.z; int bl = z / Hn, h = z % Hn;
  int b = bbase + bl;
  int nBase = blockIdx.y*32, mBase = blockIdx.x*32;
  const bf16* Qb = QKV + (long)b*Ntok*2304 + h*HD;
  const bf16* Kb = QKV + (long)b*Ntok*2304 + Dm + h*HD;
  __shared__ float Qs[32][HD+1];
  __shared__ float Ks[32][HD+1];
  int tid = threadIdx.x;
  #pragma unroll
  for (int i=0;i<8;i++){
    int e = tid + i*256;
    int r = e >> 6, c = e & 63;
    int nq = nBase + r; Qs[r][c] = (nq < Ntok) ? b2f(Qb[(long)nq*2304 + c]) : 0.f;
    int nk = mBase + r; Ks[r][c] = (nk < Ntok) ? b2f(Kb[(long)nk*2304 + c]) : 0.f;
  }
  __syncthreads();
  int tx = tid & 15, ty = tid >> 4;
  float acc[2][2]={};
  #pragma unroll 8
  for (int kk=0; kk<64; kk++){
    float a0=Qs[ty][kk], a1=Qs[ty+16][kk];
    float b0=Ks[tx][kk], b1=Ks[tx+16][kk];
    acc[0][0]+=a0*b0; acc[0][1]+=a0*b1; acc[1][0]+=a1*b0; acc[1][1]+=a1*b1;
  }
  bf16* Ab = A1 + (long)z*NN;
  #pragma unroll
  for(int i=0;i<2;i++)
  #pragma unroll
  for(int j=0;j<2;j++){
    int n=nBase+ty+16*i, m=mBase+tx+16*j;
    if(n<Ntok && m<Ntok) Ab[(long)n*Ntok+m] = __float2bfloat16(SCALE*acc[i][j]);
  }
}

// ---- talking-heads mix IN PLACE over chunk: A[bl,g,:]=sum_h A[bl,h,:]W[g,h] -
__global__ void head_mix(bf16* __restrict__ A, const void* __restrict__ W,
                         long woff, int wi, const int* __restrict__ F){
  int fw = F[wi];
  long idx = (long)blockIdx.x*256 + threadIdx.x;
  if (idx >= (long)BC*NN) return;
  int bl = (int)(idx / NN); int rem = (int)(idx % NN);
  bf16* base = A + (long)bl*Hn*NN + rem;
  float vals[Hn];
  #pragma unroll
  for (int h=0; h<Hn; h++) vals[h] = b2f(base[(long)h*NN]);
  #pragma unroll
  for (int g=0; g<Hn; g++){
    float s = 0.f;
    #pragma unroll
    for (int h=0; h<Hn; h++) s += vals[h]*ldin(W, woff + g*Hn + h, fw);
    base[(long)g*NN] = __float2bfloat16(s);
  }
}

// ---- softmax over last dim (197), one wave per row, in place ----------------
__global__ void softmax_rows(bf16* __restrict__ A){
  long row = (long)blockIdx.x*4 + (threadIdx.x>>6);
  if (row >= (long)BC*Hn*Ntok) return;
  bf16* p = A + row*Ntok;
  int lane = threadIdx.x & 63;
  float v[4];
  float mx = -1e30f;
  #pragma unroll
  for (int j=0;j<4;j++){ int i = lane + j*64; v[j] = (i<Ntok)? b2f(p[i]) : -1e30f; mx = fmaxf(mx, v[j]); }
  for (int off=32; off; off>>=1) mx = fmaxf(mx, __shfl_xor(mx, off));
  float s = 0.f;
  #pragma unroll
  for (int j=0;j<4;j++){ v[j] = expf(v[j]-mx); s += v[j]; }
  for (int off=32; off; off>>=1) s += __shfl_xor(s, off);
  float inv = 1.f/s;
  #pragma unroll
  for (int j=0;j<4;j++){ int i = lane + j*64; if (i<Ntok) p[i] = __float2bfloat16(v[j]*inv); }
}

// ---- AV (batch-chunk): o[b,n,h*64+hd] = sum_m a[bl,h,n,m]*v[b,h,m,hd] -------
__global__ void attn_av(const bf16* __restrict__ A3, const bf16* __restrict__ QKV,
                        float* __restrict__ O, int bbase){
  int z = blockIdx.y; int bl = z/Hn, h = z%Hn;
  int b = bbase + bl;
  int nBase = blockIdx.x*32;
  const bf16* Ab = A3 + (long)z*NN;
  const bf16* Vb = QKV + (long)b*Ntok*2304 + 2*Dm + h*HD;
  __shared__ float As[32][33];
  __shared__ float Vs[32][HD];
  int tid = threadIdx.x;
  int hd = tid & 63, ty = tid >> 6;
  float acc[8] = {};
  for (int m0 = 0; m0 < Ntok; m0 += 32){
    #pragma unroll
    for (int i=0;i<4;i++){
      int e = tid + i*256; int r = e>>5, c = e&31;
      int n = nBase + r, m = m0 + c;
      As[r][c] = (n<Ntok && m<Ntok) ? b2f(Ab[(long)n*Ntok+m]) : 0.f;
    }
    #pragma unroll
    for (int i=0;i<8;i++){
      int e = tid + i*256; int r = e>>6, c = e&63;
      int m = m0 + r;
      Vs[r][c] = (m<Ntok) ? b2f(Vb[(long)m*2304 + c]) : 0.f;
    }
    __syncthreads();
    #pragma unroll
    for (int kk=0; kk<32; kk++){
      float bv = Vs[kk][hd];
      #pragma unroll
      for (int i=0;i<8;i++) acc[i] += As[ty + i*4][kk]*bv;
    }
    __syncthreads();
  }
  #pragma unroll
  for (int i=0;i<8;i++){
    int n = nBase + ty + i*4;
    if (n < Ntok) O[((long)(b*Ntok + n))*Dm + h*HD + hd] = acc[i];
  }
}

// ---- head: out[b,c] = lnf(t[b,0]) . head_w[c,:] + head_b[c]  (FP32 out) -----
__global__ void head_gemm(const float* __restrict__ HF, const void* __restrict__ Wh,
                          const void* __restrict__ bh_, const int* __restrict__ F,
                          float* __restrict__ out){
  int fw = F[21], fb = F[22];
  int b = blockIdx.y;
  int c = blockIdx.x*256 + threadIdx.x;
  __shared__ float hs[Dm];
  for (int i=threadIdx.x; i<Dm; i+=256) hs[i] = HF[(long)b*Dm+i];
  __syncthreads();
  if (c >= NC) return;
  float s = ldin(bh_, c, fb);
  for (int k=0;k<Dm;k++) s += hs[k]*ldin(Wh, (long)c*Dm + k, fw);
  out[b*NC + c] = s;
}

extern "C" void kernel_launch(void* const* d_in, const int* in_sizes, int n_in,
                              void* d_out, int out_size, void* d_ws, size_t ws_size,
                              hipStream_t stream)
{
  // ---- verify/remap inputs by element count (identity if order matches) ----
  static const int EXP[23] = {4816896, 589824, 768, 768, 151296, 9216, 9216,
                              21233664, 27648, 1728, 1728, 7077888, 9216, 9216,
                              9216, 28311552, 36864, 28311552, 9216, 768, 768,
                              768000, 1000};
  const void* in[23];
  bool ident = (n_in == 23);
  if (ident) for (int i = 0; i < 23; i++) if (in_sizes[i] != EXP[i]) { ident = false; break; }
  if (ident) {
    for (int i = 0; i < 23; i++) in[i] = d_in[i];
  } else {
    bool used[64] = {};
    for (int i = 0; i < 23; i++){
      in[i] = d_in[i < n_in ? i : 0];
      for (int j = 0; j < n_in && j < 64; j++)
        if (!used[j] && in_sizes[j] == EXP[i]) { in[i] = d_in[j]; used[j] = true; break; }
    }
  }

  float* out = (float*)d_out;   // reference output dtype is float32

  // ---- Compact workspace: total 77,463,808 B = 73.9 MiB ----
  char* base = (char*)d_ws;
  int*   Fl  = (int*)base;
  float* T   = (float*)(base + 256);
  float* Hb  = (float*)(base + 19366144L);
  char*  REST=  base + 38732032L;
  float* XP  = (float*)REST;
  bf16*  QKV = (bf16*)REST;
  bf16*  Aq  = (bf16*)(REST + 29048832L);
  bf16*  M1  = (bf16*)REST;

  P23 ptrs;
  for (int i = 0; i < 23; i++) ptrs.p[i] = in[i];
  detect_k<<<23, 64, 0, stream>>>(ptrs, Fl);

  // ---- patch embed ----
  patch_extract<<<(Bb*NPATCH*Dm+255)/256, 256, 0, stream>>>(in[0], Fl, XP);
  gemm_bt<0,false,float,float><<<dim3(Dm/32, (Bb*NPATCH+31)/32), 256, 0, stream>>>(
      XP, Dm, in[1], 0, Dm, nullptr, 0, Fl, 1, -1, Hb, Dm, Bb*NPATCH, Dm, Dm);
  assemble_t<<<(TOKENS*Dm+255)/256, 256, 0, stream>>>(Hb, in[2], in[3], in[4], Fl, T);

  for (int L=0; L<DEPTH; L++){
    layernorm<<<TOKENS, 256, 0, stream>>>(T, Dm, in[5], (long)L*Dm, 5,
                                          in[6], (long)L*Dm, 6, Fl, Hb, Dm);
    gemm_bt<0,false,float,bf16><<<dim3(2304/32, TOKENS/32), 256, 0, stream>>>(
        Hb, Dm, in[7], (long)L*2304*Dm, Dm, in[8], (long)L*2304, Fl, 7, 8,
        QKV, 2304, TOKENS, 2304, Dm);
    for (int cb = 0; cb < Bb/BC; cb++){
      int bbase = cb*BC;
      attn_scores<<<dim3(7,7,BC*Hn), 256, 0, stream>>>(QKV, Aq, bbase);
      head_mix<<<(int)(((long)BC*NN+255)/256), 256, 0, stream>>>(Aq, in[9], (long)L*Hn*Hn, 9, Fl);
      softmax_rows<<<(BC*Hn*Ntok+3)/4, 256, 0, stream>>>(Aq);
      head_mix<<<(int)(((long)BC*NN+255)/256), 256, 0, stream>>>(Aq, in[10], (long)L*Hn*Hn, 10, Fl);
      attn_av<<<dim3(7, BC*Hn), 256, 0, stream>>>(Aq, QKV, Hb, bbase);
    }
    gemm_bt<0,true,float,float><<<dim3(Dm/32, TOKENS/32), 256, 0, stream>>>(
        Hb, Dm, in[11], (long)L*Dm*Dm, Dm, in[12], (long)L*Dm, Fl, 11, 12,
        T, Dm, TOKENS, Dm, Dm);
    layernorm<<<TOKENS, 256, 0, stream>>>(T, Dm, in[13], (long)L*Dm, 13,
                                          in[14], (long)L*Dm, 14, Fl, Hb, Dm);
    gemm_bt<1,false,float,bf16><<<dim3(MLPD/32, TOKENS/32), 256, 0, stream>>>(
        Hb, Dm, in[15], (long)L*MLPD*Dm, Dm, in[16], (long)L*MLPD, Fl, 15, 16,
        M1, MLPD, TOKENS, MLPD, Dm);
    gemm_bt<0,true,bf16,float><<<dim3(Dm/32, TOKENS/32), 256, 0, stream>>>(
        M1, MLPD, in[17], (long)L*Dm*MLPD, MLPD, in[18], (long)L*Dm, Fl, 17, 18,
        T, Dm, TOKENS, Dm, MLPD);
  }

  layernorm<<<Bb, 256, 0, stream>>>(T, (long)Ntok*Dm, in[19], 0, 19,
                                    in[20], 0, 20, Fl, Hb, Dm);
  head_gemm<<<dim3((NC+255)/256, Bb), 256, 0, stream>>>(Hb, in[21], in[22], Fl, out);
}